// Round 16
// baseline (321.459 us; speedup 1.0000x reference)
//
#include <hip/hip_runtime.h>
#include <cmath>

namespace {

typedef __bf16 bf16x8 __attribute__((ext_vector_type(8)));
typedef float f32x4 __attribute__((ext_vector_type(4)));
typedef unsigned short u16x8 __attribute__((ext_vector_type(8)));

enum : int { N = 128, T = 32, D = 512, H = 1024, V = 16384, R = N * T, NP = V / 64 };

// ---- workspace layout (float units) ----
enum : size_t {
  OFF_XB    = 0,                                // 4096x512 bf16
  OFF_FEATB = OFF_XB + 1048576,                 // 128x512 bf16
  OFF_H0B   = OFF_FEATB + 32768,                // 128x1024 bf16
  OFF_HALLB = OFF_H0B + 65536,                  // 4096x1024 bf16
  OFF_WPT   = OFF_HALLB + 2097152,              // 1024x512 bf16
  OFF_WXT   = OFF_WPT + 262144,                 // 1024x512 bf16
  OFF_WHT   = OFF_WXT + 262144,                 // 1024x1024 bf16
  OFF_WVT   = OFF_WHT + 524288,                 // 16384x1024 bf16
  OFF_XW    = OFF_WVT + 8388608,                // 4096x1024 f32
  OFF_PSUM  = OFF_XW + 4194304,                 // 4096x256 f32
  OFF_BLK   = OFF_PSUM + 1048576,               // 1024
  OFF_BAR   = OFF_BLK + 1024,                   // 4240 ints: 8 ctrs + 256 flags + loss ctr
};

__device__ inline unsigned short f2b(float x) {
  union { float f; unsigned u; } v; v.f = x;
  unsigned r = v.u + 0x7fffu + ((v.u >> 16) & 1u);
  return (unsigned short)(r >> 16);
}
__device__ inline float b2f(unsigned short b) {
  union { unsigned u; float f; } v; v.u = ((unsigned)b) << 16; return v.f;
}

#define GLOAD_LDS16(gptr, lptr)                                            \
  __builtin_amdgcn_global_load_lds(                                        \
      (const __attribute__((address_space(1))) unsigned int*)(gptr),       \
      (__attribute__((address_space(3))) unsigned int*)(lptr), 16, 0, 0)

__device__ inline int get_xcd() {
  int x;
  asm volatile("s_getreg_b32 %0, hwreg(HW_REG_XCC_ID)" : "=s"(x));
  return x & 7;
}

// ---------- fused preprocessing: weight transposes + gather + feat cvt ----------
// blocks [0,4608): cvt_t 64x64 tiles ([0,4096) Wv, [4096,4352) Wh,
//                  [4352,4480) Wp, [4480,4608) Wx)
// blocks [4608,8704): embedding gather+cvt ; [8704,8832): feat cvt
__global__ __launch_bounds__(256) void k_pre(
    const float* __restrict__ Wv, const float* __restrict__ Wh,
    const float* __restrict__ Wp, const float* __restrict__ Wx,
    unsigned short* __restrict__ WvT, unsigned short* __restrict__ WhT,
    unsigned short* __restrict__ WpT, unsigned short* __restrict__ WxT,
    const int* __restrict__ cap, const float* __restrict__ Wemb,
    const float* __restrict__ feat,
    unsigned short* __restrict__ XB, unsigned short* __restrict__ featB) {
  int b = blockIdx.x;
  if (b >= 4608) {
    if (b < 8704) {
      int idx = (b - 4608) * 256 + threadIdx.x;
      int r = idx >> 8;
      int w2 = (idx & 255) * 2;
      int n = r >> 5, t = r & 31;
      const float* srow = Wemb + (size_t)cap[n * 33 + t] * D;
      float2 v = *reinterpret_cast<const float2*>(srow + w2);
      ushort2 o; o.x = f2b(v.x); o.y = f2b(v.y);
      *reinterpret_cast<ushort2*>(XB + (size_t)r * D + w2) = o;
    } else {
      int i = ((b - 8704) * 256 + threadIdx.x) * 2;
      float2 v = *reinterpret_cast<const float2*>(feat + i);
      ushort2 o; o.x = f2b(v.x); o.y = f2b(v.y);
      *reinterpret_cast<ushort2*>(featB + i) = o;
    }
    return;
  }
  __shared__ float tile[64][65];
  const float* src; unsigned short* dst; int Ks, Ns, bx, by;
  if (b < 4096)      { src = Wv; dst = WvT; Ks = H; Ns = V; bx = b & 255; by = b >> 8; }
  else if (b < 4352) { int l = b - 4096; src = Wh; dst = WhT; Ks = H; Ns = H; bx = l & 15; by = l >> 4; }
  else if (b < 4480) { int l = b - 4352; src = Wp; dst = WpT; Ks = D; Ns = H; bx = l & 15; by = l >> 4; }
  else               { int l = b - 4480; src = Wx; dst = WxT; Ks = D; Ns = H; bx = l & 15; by = l >> 4; }
  const int n0 = bx * 64, k0 = by * 64;
  const int tr = threadIdx.x >> 4;
  const int tc4 = (threadIdx.x & 15) * 4;
#pragma unroll
  for (int i = 0; i < 4; ++i) {
    float4 v = *reinterpret_cast<const float4*>(
        &src[(size_t)(k0 + tr + i * 16) * Ns + n0 + tc4]);
    tile[tr + i * 16][tc4 + 0] = v.x;
    tile[tr + i * 16][tc4 + 1] = v.y;
    tile[tr + i * 16][tc4 + 2] = v.z;
    tile[tr + i * 16][tc4 + 3] = v.w;
  }
  __syncthreads();
  const int nr = threadIdx.x >> 3;
  const int k8 = (threadIdx.x & 7) * 8;
#pragma unroll
  for (int i = 0; i < 2; ++i) {
    int n = nr + i * 32;
    u16x8 o;
#pragma unroll
    for (int j = 0; j < 8; ++j) o[j] = f2b(tile[k8 + j][n]);
    *reinterpret_cast<u16x8*>(&dst[(size_t)(n0 + n) * Ks + k0 + k8]) = o;
  }
}

// ---------- bf16 MFMA GEMM: C = A * B^T (B is [N][K]), XOR-swizzled LDS ----------
// EPI: 0 = f32 store + bias; 1 = bf16 store + bias; 3 = fused row sum(exp(s-8))
template <int BM, int BN, int WM, int WN, int EPI>
__global__ __launch_bounds__(256) void gemm_bt(
    const unsigned short* __restrict__ A, int lda,
    const unsigned short* __restrict__ B, int K,
    void* __restrict__ C, int ldc,
    const float* __restrict__ bias,
    float* __restrict__ psum) {
  constexpr int BK = 64;
  constexpr int WAVES_N = BN / WN;
  constexpr int NW = (BM / WM) * (BN / WN);
  constexpr int FM = WM / 16, FN = WN / 16;
  __shared__ __align__(16) unsigned short As[BM * BK];
  __shared__ __align__(16) unsigned short Bs[BN * BK];
  int tid = threadIdx.x, lane = tid & 63, wave = tid >> 6;
  int wr = wave / WAVES_N, wc = wave % WAVES_N;

  int bx, by;
  if constexpr (EPI == 3) {
    int o = blockIdx.x;
    int r_ = o >> 3;
    bx = (o & 7) * 16 + (r_ & 15);
    by = r_ >> 4;
  } else {
    bx = blockIdx.x; by = blockIdx.y;
  }
  int row0 = by * BM, col0 = bx * BN;

  f32x4 acc[FM][FN] = {};
  const unsigned short* Ab = A + (size_t)row0 * lda;
  const unsigned short* Bb = B + (size_t)col0 * K;
  int srow = lane >> 3;
  int skof = (((lane & 7) ^ (lane >> 3))) * 8;

  for (int k0 = 0; k0 < K; k0 += BK) {
    __syncthreads();
#pragma unroll
    for (int c = wave; c < BM / 8; c += NW)
      GLOAD_LDS16(Ab + (size_t)(c * 8 + srow) * lda + k0 + skof, As + c * 512);
#pragma unroll
    for (int c = wave; c < BN / 8; c += NW)
      GLOAD_LDS16(Bb + (size_t)(c * 8 + srow) * K + k0 + skof, Bs + c * 512);
    asm volatile("s_waitcnt vmcnt(0)" ::: "memory");
    __syncthreads();
#pragma unroll
    for (int kk = 0; kk < 2; ++kk) {
      int g = ((kk * 4 + (lane >> 4)) ^ (lane & 7)) * 8;
      bf16x8 af[FM], bfr[FN];
#pragma unroll
      for (int m = 0; m < FM; ++m)
        af[m] = *reinterpret_cast<const bf16x8*>(
            &As[(wr * WM + m * 16 + (lane & 15)) * BK + g]);
#pragma unroll
      for (int n = 0; n < FN; ++n)
        bfr[n] = *reinterpret_cast<const bf16x8*>(
            &Bs[(wc * WN + n * 16 + (lane & 15)) * BK + g]);
#pragma unroll
      for (int m = 0; m < FM; ++m)
#pragma unroll
        for (int n = 0; n < FN; ++n)
          acc[m][n] = __builtin_amdgcn_mfma_f32_16x16x32_bf16(af[m], bfr[n], acc[m][n], 0, 0, 0);
    }
  }

  int lr4 = (lane >> 4) * 4, lc = lane & 15;
  if constexpr (EPI == 3) {
    // fixed-max LSE partials: psum[r][p] = sum_j exp(s - 8); exact math, f32-safe
    float bb[FN];
#pragma unroll
    for (int n = 0; n < FN; ++n) bb[n] = bias[col0 + wc * WN + n * 16 + lc] - 8.0f;
    int p = (col0 + wc * WN) >> 6;  // WN == 64
#pragma unroll
    for (int m = 0; m < FM; ++m) {
#pragma unroll
      for (int j = 0; j < 4; ++j) {
        int r = row0 + wr * WM + m * 16 + lr4 + j;
        float se = 0.f;
#pragma unroll
        for (int n = 0; n < FN; ++n) se += expf(acc[m][n][j] + bb[n]);
#pragma unroll
        for (int off = 8; off >= 1; off >>= 1) se += __shfl_xor(se, off);
        if (lc == 0) psum[(size_t)r * NP + p] = se;
      }
    }
  } else {
#pragma unroll
    for (int m = 0; m < FM; ++m)
#pragma unroll
      for (int n = 0; n < FN; ++n) {
        int cg = col0 + wc * WN + n * 16 + lc;
        float bcol = bias[cg];
#pragma unroll
        for (int j = 0; j < 4; ++j) {
          int r = row0 + wr * WM + m * 16 + lr4 + j;
          float v = acc[m][n][j] + bcol;
          if constexpr (EPI == 0) ((float*)C)[(size_t)r * ldc + cg] = v;
          else ((unsigned short*)C)[(size_t)r * ldc + cg] = f2b(v);
        }
      }
  }
}

// ---------- persistent RNN v6: XCD-LOCAL recurrences, atomic flags [R10 proven] ----------
__global__ __launch_bounds__(256, 1) void k_rnn_persist(
    const unsigned short* __restrict__ h0B,
    const unsigned short* __restrict__ WhT,   // [outcol][k] bf16
    const float* __restrict__ xW,             // [R][H] f32
    unsigned short* __restrict__ HALLB,       // [R][H] bf16
    int* __restrict__ bar) {                  // [0..127]: 8 ctrs; [128..]: 256 flags
  __shared__ __align__(16) unsigned short WhS[32 * 1024];  // 64KB: 32 cols x K
  __shared__ __align__(16) unsigned short AS[16 * 1024];   // 32KB: 16 rows x K
  __shared__ float red[2][64][4];                          // 2KB partial acc
  __shared__ int slotS;
  const int tid = threadIdx.x, lane = tid & 63, wave = tid >> 6;
  const int kh = wave >> 1, ch = wave & 1;
  const int hi = lane >> 4, lo = lane & 15;

  const int xcd = get_xcd();
  if (tid == 0)
    slotS = __hip_atomic_fetch_add(&bar[xcd * 16], 1, __ATOMIC_RELAXED,
                                   __HIP_MEMORY_SCOPE_AGENT);
  __syncthreads();
  const int slot = slotS;
  if (slot >= 32) return;

  const int n0 = xcd * 16;
  const int c0 = slot * 32;
  int* const myflag = &bar[128 + (xcd * 32 + slot) * 16];
  int* const grpflags = &bar[128 + (xcd * 32) * 16];

  for (int c = wave; c < 64; c += 4) {
    int row = c >> 1, half = c & 1;
    int sg = (half * 64 + lane) ^ (row & 7);
    GLOAD_LDS16(WhT + (size_t)(c0 + row) * 1024 + sg * 8,
                WhS + row * 1024 + half * 512);
  }

  const unsigned short* ar = AS + (size_t)lo * 1024;
  const unsigned short* br = WhS + (size_t)(ch * 16 + lo) * 1024;
  const int col = c0 + ch * 16 + lo;

  for (int t = 0; t < T; ++t) {
    const unsigned short* Aptr =
        (t == 0) ? h0B + (size_t)n0 * H : HALLB + ((size_t)n0 * T + (t - 1)) * H;
    const size_t astr = (t == 0) ? (size_t)H : (size_t)T * H;
    for (int c = wave; c < 32; c += 4) {
      int row = c >> 1, half = c & 1;
      int sg = (half * 64 + lane) ^ (row & 7);
      GLOAD_LDS16(Aptr + (size_t)row * astr + sg * 8,
                  AS + row * 1024 + half * 512);
    }
    float xw[4] = {0.f, 0.f, 0.f, 0.f};
    if (kh == 0) {
#pragma unroll
      for (int j = 0; j < 4; ++j)
        xw[j] = xW[((size_t)(n0 + hi * 4 + j) * T + t) * H + col];
    }
    asm volatile("s_waitcnt vmcnt(0)" ::: "memory");
    __syncthreads();

    f32x4 acc = {0.f, 0.f, 0.f, 0.f};
#pragma unroll
    for (int kk2 = 0; kk2 < 16; ++kk2) {
      int kk = kh * 16 + kk2;
      int g = ((kk * 4 + hi) ^ (lo & 7)) * 8;
      bf16x8 af = *reinterpret_cast<const bf16x8*>(ar + g);
      bf16x8 bf_ = *reinterpret_cast<const bf16x8*>(br + g);
      acc = __builtin_amdgcn_mfma_f32_16x16x32_bf16(af, bf_, acc, 0, 0, 0);
    }
    if (kh == 1)
      *reinterpret_cast<f32x4*>(&red[ch][lane][0]) = acc;
    __syncthreads();
    if (kh == 0) {
      f32x4 o = *reinterpret_cast<const f32x4*>(&red[ch][lane][0]);
#pragma unroll
      for (int j = 0; j < 4; ++j) {
        float v = tanhf(acc[j] + o[j] + xw[j]);
        HALLB[((size_t)(n0 + hi * 4 + j) * T + t) * H + col] = f2b(v);
      }
      asm volatile("s_waitcnt vmcnt(0)" ::: "memory");
    }
    __syncthreads();
    if (t + 1 < T) {
      if (tid == 0)
        __hip_atomic_store(myflag, t + 1, __ATOMIC_RELAXED,
                           __HIP_MEMORY_SCOPE_AGENT);
      if (tid < 32) {
        int* fp = grpflags + tid * 16;
        int iter = 0;
        while (__hip_atomic_load(fp, __ATOMIC_RELAXED,
                                 __HIP_MEMORY_SCOPE_AGENT) < t + 1 &&
               iter < (1 << 17)) {
          ++iter;
          __builtin_amdgcn_s_sleep(1);
        }
      }
      __syncthreads();
    }
  }
}

// ---------- combine partials + target dot -> nll; fused last-block final sum ----------
__global__ __launch_bounds__(256) void k_loss(const float* __restrict__ psum,
                                              const unsigned short* __restrict__ HALLB,
                                              const unsigned short* __restrict__ WvT,
                                              const float* __restrict__ bv,
                                              const int* __restrict__ cap,
                                              float* __restrict__ blk,
                                              int* __restrict__ ctr,
                                              float* __restrict__ out) {
  int wave = threadIdx.x >> 6, lane = threadIdx.x & 63;
  int r = blockIdx.x * 4 + wave;
  float S = 0.f;
  for (int i = lane; i < NP; i += 64) S += psum[(size_t)r * NP + i];
#pragma unroll
  for (int off = 32; off >= 1; off >>= 1) S += __shfl_xor(S, off);
  float lse = 8.0f + logf(S);
  int n = r >> 5, t = r & 31;
  int tok = cap[n * 33 + t + 1];
  const unsigned short* hr = HALLB + (size_t)r * H + lane * 16;
  const unsigned short* wr_ = WvT + (size_t)tok * H + lane * 16;
  float d = 0.f;
#pragma unroll
  for (int i = 0; i < 16; ++i) d += b2f(hr[i]) * b2f(wr_[i]);
#pragma unroll
  for (int off = 32; off >= 1; off >>= 1) d += __shfl_xor(d, off);
  float nll = (tok != 0) ? (lse - (d + bv[tok])) : 0.f;
  __shared__ float red[4];
  __shared__ int lastS;
  __shared__ float fin[256];
  if (lane == 0) red[wave] = nll;
  __syncthreads();
  if (threadIdx.x == 0) {
    blk[blockIdx.x] = red[0] + red[1] + red[2] + red[3];
    // ACQ_REL: release our blk store; acquire all prior blocks' stores if last
    int prev = __hip_atomic_fetch_add(ctr, 1, __ATOMIC_ACQ_REL,
                                      __HIP_MEMORY_SCOPE_AGENT);
    lastS = (prev == (R / 4) - 1);
  }
  __syncthreads();
  if (lastS) {
    float s = 0.f;
    for (int i = threadIdx.x; i < R / 4; i += 256) s += blk[i];
    fin[threadIdx.x] = s;
    __syncthreads();
    for (int st = 128; st >= 1; st >>= 1) {
      if (threadIdx.x < st) fin[threadIdx.x] += fin[threadIdx.x + st];
      __syncthreads();
    }
    if (threadIdx.x == 0) out[0] = fin[0] * (1.0f / 128.0f);
  }
}

}  // namespace

extern "C" void kernel_launch(void* const* d_in, const int* in_sizes, int n_in,
                              void* d_out, int out_size, void* d_ws, size_t ws_size,
                              hipStream_t stream) {
  const float* feat = (const float*)d_in[0];
  const int*   cap  = (const int*)d_in[1];
  const float* Wp   = (const float*)d_in[2];
  const float* bp   = (const float*)d_in[3];
  const float* Wemb = (const float*)d_in[4];
  const float* Wx   = (const float*)d_in[5];
  const float* Wh   = (const float*)d_in[6];
  const float* b    = (const float*)d_in[7];
  const float* Wv   = (const float*)d_in[8];
  const float* bv   = (const float*)d_in[9];

  float* ws = (float*)d_ws;
  unsigned short* XB    = (unsigned short*)(ws + OFF_XB);
  unsigned short* featB = (unsigned short*)(ws + OFF_FEATB);
  unsigned short* h0B   = (unsigned short*)(ws + OFF_H0B);
  unsigned short* HALLB = (unsigned short*)(ws + OFF_HALLB);
  unsigned short* WpT   = (unsigned short*)(ws + OFF_WPT);
  unsigned short* WxT   = (unsigned short*)(ws + OFF_WXT);
  unsigned short* WhT   = (unsigned short*)(ws + OFF_WHT);
  unsigned short* WvT   = (unsigned short*)(ws + OFF_WVT);
  float* xW   = ws + OFF_XW;
  float* psum = ws + OFF_PSUM;
  float* blk  = ws + OFF_BLK;
  int*   bar  = (int*)(ws + OFF_BAR);

  hipMemsetAsync(bar, 0, 4240 * sizeof(int), stream);

  // fused preprocessing: all weight transposes + gather + feat cvt, one dispatch
  hipLaunchKernelGGL(k_pre, dim3(8832), dim3(256), 0, stream,
                     Wv, Wh, Wp, Wx, WvT, WhT, WpT, WxT, cap, Wemb, feat, XB, featB);

  // h0 = featB @ Wp^T + bp   (bf16 out)
  hipLaunchKernelGGL((gemm_bt<128, 128, 64, 64, 1>), dim3(H / 128, 1), dim3(256), 0, stream,
                     featB, D, WpT, D, (void*)h0B, H, bp, nullptr);
  // xW = XB @ Wx^T + b   (f32 out)
  hipLaunchKernelGGL((gemm_bt<128, 128, 64, 64, 0>), dim3(H / 128, R / 128), dim3(256), 0, stream,
                     XB, D, WxT, D, (void*)xW, H, b, nullptr);
  // full recurrence: 8 independent XCD-local RNNs, one dispatch
  hipLaunchKernelGGL(k_rnn_persist, dim3(256), dim3(256), 0, stream,
                     h0B, WhT, xW, HALLB, bar);
  // scores partials: 2-phase swizzled GEMM, XCD-aware 1-D grid, fixed-max LSE
  hipLaunchKernelGGL((gemm_bt<128, 128, 64, 64, 3>), dim3((V / 128) * (R / 128)), dim3(256), 0, stream,
                     HALLB, H, WvT, H, nullptr, 0, bv, psum);
  // loss combine + fused final reduction (last-block pattern; ctr at bar[4224])
  hipLaunchKernelGGL(k_loss, dim3(R / 4), dim3(256), 0, stream,
                     psum, HALLB, WvT, bv, cap, blk, bar + 4224, (float*)d_out);
}

// Round 17
// 301.658 us; speedup vs baseline: 1.0656x; 1.0656x over previous
//
#include <hip/hip_runtime.h>
#include <cmath>

namespace {

typedef __bf16 bf16x8 __attribute__((ext_vector_type(8)));
typedef float f32x4 __attribute__((ext_vector_type(4)));
typedef unsigned short u16x8 __attribute__((ext_vector_type(8)));

enum : int { N = 128, T = 32, D = 512, H = 1024, V = 16384, R = N * T, NP = V / 64 };

// ---- workspace layout (float units) ----
enum : size_t {
  OFF_XB    = 0,                                // 4096x512 bf16
  OFF_FEATB = OFF_XB + 1048576,                 // 128x512 bf16
  OFF_H0B   = OFF_FEATB + 32768,                // 128x1024 bf16
  OFF_HALLB = OFF_H0B + 65536,                  // 4096x1024 bf16
  OFF_WPT   = OFF_HALLB + 2097152,              // 1024x512 bf16
  OFF_WXT   = OFF_WPT + 262144,                 // 1024x512 bf16
  OFF_WHT   = OFF_WXT + 262144,                 // 1024x1024 bf16
  OFF_WVT   = OFF_WHT + 524288,                 // 16384x1024 bf16
  OFF_XW    = OFF_WVT + 8388608,                // 4096x1024 f32
  OFF_PSUM  = OFF_XW + 4194304,                 // 4096x256 f32
  OFF_BLK   = OFF_PSUM + 1048576,               // 1024
  OFF_BAR   = OFF_BLK + 1024,                   // 4224 ints: 8 ctrs + 256 flags, 64B apart
};

__device__ inline unsigned short f2b(float x) {
  union { float f; unsigned u; } v; v.f = x;
  unsigned r = v.u + 0x7fffu + ((v.u >> 16) & 1u);
  return (unsigned short)(r >> 16);
}
__device__ inline float b2f(unsigned short b) {
  union { unsigned u; float f; } v; v.u = ((unsigned)b) << 16; return v.f;
}

#define GLOAD_LDS16(gptr, lptr)                                            \
  __builtin_amdgcn_global_load_lds(                                        \
      (const __attribute__((address_space(1))) unsigned int*)(gptr),       \
      (__attribute__((address_space(3))) unsigned int*)(lptr), 16, 0, 0)

__device__ inline int get_xcd() {
  int x;
  asm volatile("s_getreg_b32 %0, hwreg(HW_REG_XCC_ID)" : "=s"(x));
  return x & 7;
}

// ---------- all weight transposes fused: dst[n][k] = bf16(src[k][n]) ----------
// segments (64x64 tiles): [0,4096) Wv, [4096,4352) Wh, [4352,4480) Wp, [4480,4608) Wx
__global__ __launch_bounds__(256) void k_cvt_t_all(
    const float* __restrict__ Wv, const float* __restrict__ Wh,
    const float* __restrict__ Wp, const float* __restrict__ Wx,
    unsigned short* __restrict__ WvT, unsigned short* __restrict__ WhT,
    unsigned short* __restrict__ WpT, unsigned short* __restrict__ WxT) {
  __shared__ float tile[64][65];
  const float* src; unsigned short* dst; int Ks, Ns, bx, by;
  int b = blockIdx.x;
  if (b < 4096)      { src = Wv; dst = WvT; Ks = H; Ns = V; bx = b & 255; by = b >> 8; }
  else if (b < 4352) { int l = b - 4096; src = Wh; dst = WhT; Ks = H; Ns = H; bx = l & 15; by = l >> 4; }
  else if (b < 4480) { int l = b - 4352; src = Wp; dst = WpT; Ks = D; Ns = H; bx = l & 15; by = l >> 4; }
  else               { int l = b - 4480; src = Wx; dst = WxT; Ks = D; Ns = H; bx = l & 15; by = l >> 4; }
  const int n0 = bx * 64, k0 = by * 64;
  const int tr = threadIdx.x >> 4;
  const int tc4 = (threadIdx.x & 15) * 4;
#pragma unroll
  for (int i = 0; i < 4; ++i) {
    float4 v = *reinterpret_cast<const float4*>(
        &src[(size_t)(k0 + tr + i * 16) * Ns + n0 + tc4]);
    tile[tr + i * 16][tc4 + 0] = v.x;
    tile[tr + i * 16][tc4 + 1] = v.y;
    tile[tr + i * 16][tc4 + 2] = v.z;
    tile[tr + i * 16][tc4 + 3] = v.w;
  }
  __syncthreads();
  const int nr = threadIdx.x >> 3;
  const int k8 = (threadIdx.x & 7) * 8;
#pragma unroll
  for (int i = 0; i < 2; ++i) {
    int n = nr + i * 32;
    u16x8 o;
#pragma unroll
    for (int j = 0; j < 8; ++j) o[j] = f2b(tile[k8 + j][n]);
    *reinterpret_cast<u16x8*>(&dst[(size_t)(n0 + n) * Ks + k0 + k8]) = o;
  }
}

// ---------- fused: embedding gather+cvt [0,4096) | feat cvt [4096,4224) ----------
__global__ __launch_bounds__(256) void k_inputs(const int* __restrict__ cap,
                                                const float* __restrict__ Wemb,
                                                const float* __restrict__ feat,
                                                unsigned short* __restrict__ XB,
                                                unsigned short* __restrict__ featB) {
  if (blockIdx.x < 4096) {
    int idx = blockIdx.x * 256 + threadIdx.x;
    int r = idx >> 8;
    int w2 = (idx & 255) * 2;
    int n = r >> 5, t = r & 31;
    const float* srow = Wemb + (size_t)cap[n * 33 + t] * D;
    float2 v = *reinterpret_cast<const float2*>(srow + w2);
    ushort2 o; o.x = f2b(v.x); o.y = f2b(v.y);
    *reinterpret_cast<ushort2*>(XB + (size_t)r * D + w2) = o;
  } else {
    int i = ((blockIdx.x - 4096) * 256 + threadIdx.x) * 2;
    float2 v = *reinterpret_cast<const float2*>(feat + i);
    ushort2 o; o.x = f2b(v.x); o.y = f2b(v.y);
    *reinterpret_cast<ushort2*>(featB + i) = o;
  }
}

// ---------- bf16 MFMA GEMM: C = A * B^T (B is [N][K]), XOR-swizzled LDS ----------
// EPI: 0 = f32 store + bias; 1 = bf16 store + bias; 3 = fused row sum(exp(s-8))
template <int BM, int BN, int WM, int WN, int EPI>
__global__ __launch_bounds__(256) void gemm_bt(
    const unsigned short* __restrict__ A, int lda,
    const unsigned short* __restrict__ B, int K,
    void* __restrict__ C, int ldc,
    const float* __restrict__ bias,
    float* __restrict__ psum) {
  constexpr int BK = 64;
  constexpr int WAVES_N = BN / WN;
  constexpr int NW = (BM / WM) * (BN / WN);
  constexpr int FM = WM / 16, FN = WN / 16;
  __shared__ __align__(16) unsigned short As[BM * BK];
  __shared__ __align__(16) unsigned short Bs[BN * BK];
  int tid = threadIdx.x, lane = tid & 63, wave = tid >> 6;
  int wr = wave / WAVES_N, wc = wave % WAVES_N;

  int bx, by;
  if constexpr (EPI == 3) {
    int o = blockIdx.x;
    int r_ = o >> 3;
    bx = (o & 7) * 16 + (r_ & 15);
    by = r_ >> 4;
  } else {
    bx = blockIdx.x; by = blockIdx.y;
  }
  int row0 = by * BM, col0 = bx * BN;

  f32x4 acc[FM][FN] = {};
  const unsigned short* Ab = A + (size_t)row0 * lda;
  const unsigned short* Bb = B + (size_t)col0 * K;
  int srow = lane >> 3;
  int skof = (((lane & 7) ^ (lane >> 3))) * 8;

  for (int k0 = 0; k0 < K; k0 += BK) {
    __syncthreads();
#pragma unroll
    for (int c = wave; c < BM / 8; c += NW)
      GLOAD_LDS16(Ab + (size_t)(c * 8 + srow) * lda + k0 + skof, As + c * 512);
#pragma unroll
    for (int c = wave; c < BN / 8; c += NW)
      GLOAD_LDS16(Bb + (size_t)(c * 8 + srow) * K + k0 + skof, Bs + c * 512);
    asm volatile("s_waitcnt vmcnt(0)" ::: "memory");
    __syncthreads();
#pragma unroll
    for (int kk = 0; kk < 2; ++kk) {
      int g = ((kk * 4 + (lane >> 4)) ^ (lane & 7)) * 8;
      bf16x8 af[FM], bfr[FN];
#pragma unroll
      for (int m = 0; m < FM; ++m)
        af[m] = *reinterpret_cast<const bf16x8*>(
            &As[(wr * WM + m * 16 + (lane & 15)) * BK + g]);
#pragma unroll
      for (int n = 0; n < FN; ++n)
        bfr[n] = *reinterpret_cast<const bf16x8*>(
            &Bs[(wc * WN + n * 16 + (lane & 15)) * BK + g]);
#pragma unroll
      for (int m = 0; m < FM; ++m)
#pragma unroll
        for (int n = 0; n < FN; ++n)
          acc[m][n] = __builtin_amdgcn_mfma_f32_16x16x32_bf16(af[m], bfr[n], acc[m][n], 0, 0, 0);
    }
  }

  int lr4 = (lane >> 4) * 4, lc = lane & 15;
  if constexpr (EPI == 3) {
    // fixed-max LSE partials: psum[r][p] = sum_j exp(s - 8); exact math, f32-safe
    float bb[FN];
#pragma unroll
    for (int n = 0; n < FN; ++n) bb[n] = bias[col0 + wc * WN + n * 16 + lc] - 8.0f;
    int p = (col0 + wc * WN) >> 6;  // WN == 64
#pragma unroll
    for (int m = 0; m < FM; ++m) {
#pragma unroll
      for (int j = 0; j < 4; ++j) {
        int r = row0 + wr * WM + m * 16 + lr4 + j;
        float se = 0.f;
#pragma unroll
        for (int n = 0; n < FN; ++n) se += expf(acc[m][n][j] + bb[n]);
#pragma unroll
        for (int off = 8; off >= 1; off >>= 1) se += __shfl_xor(se, off);
        if (lc == 0) psum[(size_t)r * NP + p] = se;
      }
    }
  } else {
#pragma unroll
    for (int m = 0; m < FM; ++m)
#pragma unroll
      for (int n = 0; n < FN; ++n) {
        int cg = col0 + wc * WN + n * 16 + lc;
        float bcol = bias[cg];
#pragma unroll
        for (int j = 0; j < 4; ++j) {
          int r = row0 + wr * WM + m * 16 + lr4 + j;
          float v = acc[m][n][j] + bcol;
          if constexpr (EPI == 0) ((float*)C)[(size_t)r * ldc + cg] = v;
          else ((unsigned short*)C)[(size_t)r * ldc + cg] = f2b(v);
        }
      }
  }
}

// ---------- persistent RNN v6: XCD-LOCAL recurrences, atomic flags [R10 proven] ----------
__global__ __launch_bounds__(256, 1) void k_rnn_persist(
    const unsigned short* __restrict__ h0B,
    const unsigned short* __restrict__ WhT,   // [outcol][k] bf16
    const float* __restrict__ xW,             // [R][H] f32
    unsigned short* __restrict__ HALLB,       // [R][H] bf16
    int* __restrict__ bar) {                  // [0..127]: 8 ctrs; [128..]: 256 flags
  __shared__ __align__(16) unsigned short WhS[32 * 1024];  // 64KB: 32 cols x K
  __shared__ __align__(16) unsigned short AS[16 * 1024];   // 32KB: 16 rows x K
  __shared__ float red[2][64][4];                          // 2KB partial acc
  __shared__ int slotS;
  const int tid = threadIdx.x, lane = tid & 63, wave = tid >> 6;
  const int kh = wave >> 1, ch = wave & 1;
  const int hi = lane >> 4, lo = lane & 15;

  const int xcd = get_xcd();
  if (tid == 0)
    slotS = __hip_atomic_fetch_add(&bar[xcd * 16], 1, __ATOMIC_RELAXED,
                                   __HIP_MEMORY_SCOPE_AGENT);
  __syncthreads();
  const int slot = slotS;
  if (slot >= 32) return;

  const int n0 = xcd * 16;
  const int c0 = slot * 32;
  int* const myflag = &bar[128 + (xcd * 32 + slot) * 16];
  int* const grpflags = &bar[128 + (xcd * 32) * 16];

  for (int c = wave; c < 64; c += 4) {
    int row = c >> 1, half = c & 1;
    int sg = (half * 64 + lane) ^ (row & 7);
    GLOAD_LDS16(WhT + (size_t)(c0 + row) * 1024 + sg * 8,
                WhS + row * 1024 + half * 512);
  }

  const unsigned short* ar = AS + (size_t)lo * 1024;
  const unsigned short* br = WhS + (size_t)(ch * 16 + lo) * 1024;
  const int col = c0 + ch * 16 + lo;

  for (int t = 0; t < T; ++t) {
    const unsigned short* Aptr =
        (t == 0) ? h0B + (size_t)n0 * H : HALLB + ((size_t)n0 * T + (t - 1)) * H;
    const size_t astr = (t == 0) ? (size_t)H : (size_t)T * H;
    for (int c = wave; c < 32; c += 4) {
      int row = c >> 1, half = c & 1;
      int sg = (half * 64 + lane) ^ (row & 7);
      GLOAD_LDS16(Aptr + (size_t)row * astr + sg * 8,
                  AS + row * 1024 + half * 512);
    }
    float xw[4] = {0.f, 0.f, 0.f, 0.f};
    if (kh == 0) {
#pragma unroll
      for (int j = 0; j < 4; ++j)
        xw[j] = xW[((size_t)(n0 + hi * 4 + j) * T + t) * H + col];
    }
    asm volatile("s_waitcnt vmcnt(0)" ::: "memory");
    __syncthreads();

    f32x4 acc = {0.f, 0.f, 0.f, 0.f};
#pragma unroll
    for (int kk2 = 0; kk2 < 16; ++kk2) {
      int kk = kh * 16 + kk2;
      int g = ((kk * 4 + hi) ^ (lo & 7)) * 8;
      bf16x8 af = *reinterpret_cast<const bf16x8*>(ar + g);
      bf16x8 bf_ = *reinterpret_cast<const bf16x8*>(br + g);
      acc = __builtin_amdgcn_mfma_f32_16x16x32_bf16(af, bf_, acc, 0, 0, 0);
    }
    if (kh == 1)
      *reinterpret_cast<f32x4*>(&red[ch][lane][0]) = acc;
    __syncthreads();
    if (kh == 0) {
      f32x4 o = *reinterpret_cast<const f32x4*>(&red[ch][lane][0]);
#pragma unroll
      for (int j = 0; j < 4; ++j) {
        float v = tanhf(acc[j] + o[j] + xw[j]);
        HALLB[((size_t)(n0 + hi * 4 + j) * T + t) * H + col] = f2b(v);
      }
      asm volatile("s_waitcnt vmcnt(0)" ::: "memory");
    }
    __syncthreads();
    if (t + 1 < T) {
      if (tid == 0)
        __hip_atomic_store(myflag, t + 1, __ATOMIC_RELAXED,
                           __HIP_MEMORY_SCOPE_AGENT);
      if (tid < 32) {
        int* fp = grpflags + tid * 16;
        int iter = 0;
        while (__hip_atomic_load(fp, __ATOMIC_RELAXED,
                                 __HIP_MEMORY_SCOPE_AGENT) < t + 1 &&
               iter < (1 << 17)) {
          ++iter;
          __builtin_amdgcn_s_sleep(1);
        }
      }
      __syncthreads();
    }
  }
}

// ---------- combine partials + target dot -> per-block nll sums ----------
__global__ __launch_bounds__(256) void k_loss(const float* __restrict__ psum,
                                              const unsigned short* __restrict__ HALLB,
                                              const unsigned short* __restrict__ WvT,
                                              const float* __restrict__ bv,
                                              const int* __restrict__ cap,
                                              float* __restrict__ blk) {
  int wave = threadIdx.x >> 6, lane = threadIdx.x & 63;
  int r = blockIdx.x * 4 + wave;
  float S = 0.f;
  for (int i = lane; i < NP; i += 64) S += psum[(size_t)r * NP + i];
#pragma unroll
  for (int off = 32; off >= 1; off >>= 1) S += __shfl_xor(S, off);
  float lse = 8.0f + logf(S);
  int n = r >> 5, t = r & 31;
  int tok = cap[n * 33 + t + 1];
  const unsigned short* hr = HALLB + (size_t)r * H + lane * 16;
  const unsigned short* wr_ = WvT + (size_t)tok * H + lane * 16;
  float d = 0.f;
#pragma unroll
  for (int i = 0; i < 16; ++i) d += b2f(hr[i]) * b2f(wr_[i]);
#pragma unroll
  for (int off = 32; off >= 1; off >>= 1) d += __shfl_xor(d, off);
  float nll = (tok != 0) ? (lse - (d + bv[tok])) : 0.f;
  __shared__ float red[4];
  if (lane == 0) red[wave] = nll;
  __syncthreads();
  if (threadIdx.x == 0) blk[blockIdx.x] = red[0] + red[1] + red[2] + red[3];
}

__global__ __launch_bounds__(256) void k_final(const float* __restrict__ blk,
                                               float* __restrict__ out) {
  __shared__ float red[256];
  float s = 0.f;
  for (int i = threadIdx.x; i < R / 4; i += 256) s += blk[i];
  red[threadIdx.x] = s;
  __syncthreads();
  for (int st = 128; st >= 1; st >>= 1) {
    if (threadIdx.x < st) red[threadIdx.x] += red[threadIdx.x + st];
    __syncthreads();
  }
  if (threadIdx.x == 0) out[0] = red[0] * (1.0f / 128.0f);
}

}  // namespace

extern "C" void kernel_launch(void* const* d_in, const int* in_sizes, int n_in,
                              void* d_out, int out_size, void* d_ws, size_t ws_size,
                              hipStream_t stream) {
  const float* feat = (const float*)d_in[0];
  const int*   cap  = (const int*)d_in[1];
  const float* Wp   = (const float*)d_in[2];
  const float* bp   = (const float*)d_in[3];
  const float* Wemb = (const float*)d_in[4];
  const float* Wx   = (const float*)d_in[5];
  const float* Wh   = (const float*)d_in[6];
  const float* b    = (const float*)d_in[7];
  const float* Wv   = (const float*)d_in[8];
  const float* bv   = (const float*)d_in[9];

  float* ws = (float*)d_ws;
  unsigned short* XB    = (unsigned short*)(ws + OFF_XB);
  unsigned short* featB = (unsigned short*)(ws + OFF_FEATB);
  unsigned short* h0B   = (unsigned short*)(ws + OFF_H0B);
  unsigned short* HALLB = (unsigned short*)(ws + OFF_HALLB);
  unsigned short* WpT   = (unsigned short*)(ws + OFF_WPT);
  unsigned short* WxT   = (unsigned short*)(ws + OFF_WXT);
  unsigned short* WhT   = (unsigned short*)(ws + OFF_WHT);
  unsigned short* WvT   = (unsigned short*)(ws + OFF_WVT);
  float* xW   = ws + OFF_XW;
  float* psum = ws + OFF_PSUM;
  float* blk  = ws + OFF_BLK;
  int*   bar  = (int*)(ws + OFF_BAR);

  hipMemsetAsync(bar, 0, 4224 * sizeof(int), stream);

  // all weight transposes in one dispatch; inputs (gather + feat cvt) in one
  hipLaunchKernelGGL(k_cvt_t_all, dim3(4608), dim3(256), 0, stream,
                     Wv, Wh, Wp, Wx, WvT, WhT, WpT, WxT);
  hipLaunchKernelGGL(k_inputs, dim3(4224), dim3(256), 0, stream,
                     cap, Wemb, feat, XB, featB);

  // h0 = featB @ Wp^T + bp   (bf16 out)
  hipLaunchKernelGGL((gemm_bt<128, 128, 64, 64, 1>), dim3(H / 128, 1), dim3(256), 0, stream,
                     featB, D, WpT, D, (void*)h0B, H, bp, nullptr);
  // xW = XB @ Wx^T + b   (f32 out)
  hipLaunchKernelGGL((gemm_bt<128, 128, 64, 64, 0>), dim3(H / 128, R / 128), dim3(256), 0, stream,
                     XB, D, WxT, D, (void*)xW, H, b, nullptr);
  // full recurrence: 8 independent XCD-local RNNs, one dispatch
  hipLaunchKernelGGL(k_rnn_persist, dim3(256), dim3(256), 0, stream,
                     h0B, WhT, xW, HALLB, bar);
  // scores partials: 2-phase swizzled GEMM, XCD-aware 1-D grid, fixed-max LSE
  hipLaunchKernelGGL((gemm_bt<128, 128, 64, 64, 3>), dim3((V / 128) * (R / 128)), dim3(256), 0, stream,
                     HALLB, H, WvT, H, nullptr, 0, bv, psum);
  hipLaunchKernelGGL(k_loss, dim3(R / 4), dim3(256), 0, stream,
                     psum, HALLB, WvT, bv, cap, blk);
  hipLaunchKernelGGL(k_final, dim3(1), dim3(256), 0, stream, blk, (float*)d_out);
}